// Round 7
// baseline (288.631 us; speedup 1.0000x reference)
//
#include <hip/hip_runtime.h>
#include <hip/hip_bf16.h>

#define N_NODES 50000
#define N_EDGES 800000
#define IN_DIM  256
#define HID     128
#define LEAKY   0.01f

#define EDGE_BLOCKS  ((N_EDGES + 255) / 256)      // 3125
#define NODE_WBLKS   (N_NODES / 4)                // 12500
#define SCAN_BLOCKS  ((N_NODES + 255) / 256)      // 196
#define W1_ELEMS  (HID * IN_DIM)                  // 32768
#define W2_ELEMS  (HID * HID)                     // 16384

#define TM        64                              // GEMM rows per block
#define FC_BLOCKS ((N_NODES + TM - 1) / TM)       // 782

typedef __attribute__((ext_vector_type(8))) short short8;
typedef __attribute__((ext_vector_type(4))) float f32x4;

// async global->LDS, 16B per lane; dest = wave-uniform base + lane*16 (m97 pattern)
#define GLDS(g, l)                                                              \
    __builtin_amdgcn_global_load_lds(                                           \
        (const __attribute__((address_space(1))) void*)(g),                     \
        (__attribute__((address_space(3))) void*)(l), 16, 0, 0)

__device__ __forceinline__ unsigned short f2bf(float x) {
    union { __hip_bfloat16 b; unsigned short u; } c;
    c.b = __float2bfloat16(x);
    return c.u;
}
__device__ __forceinline__ float bf2f(unsigned short u) {
    union { unsigned int u; float f; } c;
    c.u = ((unsigned int)u) << 16;
    return c.f;
}
__device__ __forceinline__ float2 bfu2(unsigned int u) {
    float2 r;
    r.x = bf2f((unsigned short)(u & 0xffff));
    r.y = bf2f((unsigned short)(u >> 16));
    return r;
}
__device__ __forceinline__ float lky(float x) { return x > 0.f ? x : LEAKY * x; }
__device__ __forceinline__ float rl_f(float v, int l) {
    return __int_as_float(__builtin_amdgcn_readlane(__float_as_int(v), l));
}

// split 8 fp32 into bf16 hi/lo (same op order as original -> identical numerics)
__device__ __forceinline__ void cvt8(const float4 v0, const float4 v1,
                                     short8& hi, short8& lo) {
    float f[8] = {v0.x, v0.y, v0.z, v0.w, v1.x, v1.y, v1.z, v1.w};
#pragma unroll
    for (int j = 0; j < 8; j++) {
        unsigned short h = f2bf(f[j]);
        hi[j] = (short)h;
        lo[j] = (short)f2bf(f[j] - bf2f(h));
    }
}

// ------- CSR hist (rank-returning) + W splits (fused, independent work) --------

__global__ void hist_split(const int* __restrict__ dst, int* __restrict__ counts,
                           int* __restrict__ erank,
                           const float* __restrict__ W1, unsigned short* __restrict__ w1hi,
                           unsigned short* __restrict__ w1lo,
                           const float* __restrict__ W2, unsigned short* __restrict__ w2hi,
                           unsigned short* __restrict__ w2lo) {
    int i = blockIdx.x * 256 + threadIdx.x;
    if (i < N_EDGES) erank[i] = atomicAdd(&counts[dst[i]], 1);
    if (i < W1_ELEMS) {
        float x = W1[i];
        unsigned short h = f2bf(x);
        w1hi[i] = h;
        w1lo[i] = f2bf(x - bf2f(h));
    } else if (i < W1_ELEMS + W2_ELEMS) {
        int j = i - W1_ELEMS;
        float x = W2[j];
        unsigned short h = f2bf(x);
        w2hi[j] = h;
        w2lo[j] = f2bf(x - bf2f(h));
    }
}

__global__ void scan_block(const int* __restrict__ counts, int* __restrict__ offsets,
                           int* __restrict__ bsums) {
    __shared__ int sh[256];
    int tid = threadIdx.x;
    int i = blockIdx.x * 256 + tid;
    int v = (i < N_NODES) ? counts[i] : 0;
    sh[tid] = v;
    __syncthreads();
    for (int o = 1; o < 256; o <<= 1) {
        int t = (tid >= o) ? sh[tid - o] : 0;
        __syncthreads();
        sh[tid] += t;
        __syncthreads();
    }
    if (i < N_NODES) offsets[i] = sh[tid] - v;
    if (tid == 255) bsums[blockIdx.x] = sh[255];
}

__global__ void scan_add(int* __restrict__ offsets, const int* __restrict__ bsums) {
    __shared__ int sh[256];
    int tid = threadIdx.x;
    int b = blockIdx.x;
    sh[tid] = (tid < b) ? bsums[tid] : 0;   // b <= 195 < 256
    __syncthreads();
    for (int o = 128; o > 0; o >>= 1) {
        if (tid < o) sh[tid] += sh[tid + o];
        __syncthreads();
    }
    int base = sh[0];
    int i = b * 256 + tid;
    if (i < N_NODES) offsets[i] += base;
    if (i == N_NODES) offsets[N_NODES] = N_EDGES;
}

// fill: atomic-free scatter; nontemporal store avoids cross-XCD L2 line bounce
__global__ void fill_kernel(const int* __restrict__ dst, const int* __restrict__ src,
                            const int* __restrict__ erank,
                            const int* __restrict__ offsets,
                            int* __restrict__ csr_src) {
    int i = blockIdx.x * 256 + threadIdx.x;
    if (i < N_EDGES) {
        int d = dst[i];
        int slot = offsets[d] + erank[i];
        __builtin_nontemporal_store(src[i], &csr_src[slot]);
    }
}

// ---------------- epilogue for one 16-row subtile ----------------
// C/D: col = lane&15, row = (lane>>4)*4 + reg. Partial scores reduce over r
// via shfl_xor, then land in sbuf[q*128 + {0:S,64:D} + lrow] for block-combine.

__device__ __forceinline__ void epi(const f32x4* accn, int lrow0, int m0, int q, int lane,
                                    const float* __restrict__ bias,
                                    const float* __restrict__ attn,
                                    unsigned short* __restrict__ Zb,
                                    float* __restrict__ sbuf) {
    int r = lane & 15;
    int lrowbase = lrow0 + (lane >> 4) * 4;   // 0..63 within block
    float ps[4] = {0.f, 0.f, 0.f, 0.f};
    float pd[4] = {0.f, 0.f, 0.f, 0.f};
#pragma unroll
    for (int nt = 0; nt < 4; nt++) {
        int n = q * 64 + nt * 16 + r;
        float bn = bias[n];
        float aS = attn[n];
        float aD = attn[HID + n];
#pragma unroll
        for (int reg = 0; reg < 4; reg++) {
            float zv = accn[nt][reg] + bn;
            if (m0 + lrowbase + reg < N_NODES)
                Zb[(size_t)(m0 + lrowbase + reg) * HID + n] = f2bf(zv);
            ps[reg] += zv * aS;
            pd[reg] += zv * aD;
        }
    }
#pragma unroll
    for (int o = 1; o < 16; o <<= 1) {
#pragma unroll
        for (int reg = 0; reg < 4; reg++) {
            ps[reg] += __shfl_xor(ps[reg], o, 64);
            pd[reg] += __shfl_xor(pd[reg], o, 64);
        }
    }
    if (r == 0) {
#pragma unroll
        for (int reg = 0; reg < 4; reg++) {
            sbuf[q * 128 + lrowbase + reg] = ps[reg];
            sbuf[q * 128 + 64 + lrowbase + reg] = pd[reg];
        }
    }
}

// combine q-halves and store single score planes
__device__ __forceinline__ void score_combine(const float* __restrict__ sbuf, int tid, int m0,
                                              float* __restrict__ sS, float* __restrict__ sD) {
    if (tid < TM) {
        int gr = m0 + tid;
        if (gr < N_NODES) {
            sS[gr] = sbuf[tid] + sbuf[128 + tid];
            sD[gr] = sbuf[64 + tid] + sbuf[128 + 64 + tid];
        }
    }
}

// ------- FC1: counted-vmcnt with ASYMMETRIC buffering to fit 2 blocks/CU:
// A (L3/HBM, long latency): triple-buffered, lead-2 (3x8KB).
// B (W planes, L2-resident): double-buffered, lead-1 (2x16KB). Total 56KB.
// Per iter: wait vmcnt(2) [queue oldest->newest: A(kt)2,B(kt)4,A(kt+1)2 ->
// retires A(kt)+B(kt), leaves A(kt+1)], raw barrier, issue B(kt+1) then
// A(kt+2), compute. Issue order (prologue A0,B0,A1; per-iter B-then-A)
// makes the oldest-first vmcnt arithmetic exact. 4 waves; 2 independent
// blocks/CU cover each other's barrier stalls. -------

__launch_bounds__(256)
__global__ void gemm_fc1(const float* __restrict__ A,
                         const unsigned short* __restrict__ Whi,
                         const unsigned short* __restrict__ Wlo,
                         const float* __restrict__ bias,
                         const float* __restrict__ attn,
                         unsigned short* __restrict__ Zb,
                         float* __restrict__ sS, float* __restrict__ sD) {
    __shared__ char Abuf[3][8192];
    __shared__ char Bbuf[2][16384];

    int tid  = threadIdx.x;
    int lane = tid & 63;
    int w    = tid >> 6;       // 0..3
    int q    = w & 1;
    int mh   = w >> 1;
    int m0   = blockIdx.x * TM;
    int r    = lane & 15;
    int kg   = lane >> 4;

    // A: 2 chunks/wave (c = 2w+j: S=w, half=j). fragment-order (R4-verified).
    const char* gpA[2];
    int loffA[2];
#pragma unroll
    for (int j = 0; j < 2; j++) {
        int row = m0 + w * 16 + r;
        if (row >= N_NODES) row = N_NODES - 1;
        gpA[j] = (const char*)(A + (size_t)row * IN_DIM + kg * 8 + j * 4);
        loffA[j] = (w * 2 + j) * 1024;
    }
    // B: 4 chunks/wave (c = 4w+j; c<8: hi nt=c; else lo nt=c-8).
    const char* gpB[4];
    int loffB[4];
#pragma unroll
    for (int j = 0; j < 4; j++) {
        int c = w * 4 + j;
        loffB[j] = c * 1024;
        if (c < 8) {
            gpB[j] = (const char*)(Whi + (size_t)(c * 16 + r) * IN_DIM + kg * 8);
        } else {
            gpB[j] = (const char*)(Wlo + (size_t)((c - 8) * 16 + r) * IN_DIM + kg * 8);
        }
    }

#define STAGE_A1(b)                                                 \
    {                                                               \
        _Pragma("unroll") for (int j = 0; j < 2; j++) {             \
            GLDS(gpA[j], Abuf[b] + loffA[j]);                       \
            gpA[j] += 128;                                          \
        }                                                           \
    }
#define STAGE_B1(b)                                                 \
    {                                                               \
        _Pragma("unroll") for (int j = 0; j < 4; j++) {             \
            GLDS(gpB[j], Bbuf[b] + loffB[j]);                       \
            gpB[j] += 64;                                           \
        }                                                           \
    }

    f32x4 acc[2][4];
#pragma unroll
    for (int s = 0; s < 2; s++)
#pragma unroll
        for (int nt = 0; nt < 4; nt++) acc[s][nt] = (f32x4){0.f, 0.f, 0.f, 0.f};

    const int NT = IN_DIM / 32;            // 8
    STAGE_A1(0);
    STAGE_B1(0);
    STAGE_A1(1);

#pragma unroll
    for (int kt = 0; kt < NT; kt++) {
        if (kt < NT - 1) {
            asm volatile("s_waitcnt vmcnt(2)" ::: "memory");  // A(kt)+B(kt) done
        } else {
            asm volatile("s_waitcnt vmcnt(0)" ::: "memory");
        }
        __builtin_amdgcn_s_barrier();
        __builtin_amdgcn_sched_barrier(0);
        if (kt + 1 < NT) STAGE_B1((kt + 1) & 1);      // after barrier: race-free
        if (kt + 2 < NT) STAGE_A1((kt + 2) % 3);

        const char* Ab = Abuf[kt % 3];
        const char* Bb = Bbuf[kt & 1];

        short8 ah[2], al[2], bh[4], bl[4];
#pragma unroll
        for (int s = 0; s < 2; s++) {
            int S = mh * 2 + s;
            float4 v0 = *(const float4*)(Ab + (S * 2 + 0) * 1024 + lane * 16);
            float4 v1 = *(const float4*)(Ab + (S * 2 + 1) * 1024 + lane * 16);
            cvt8(v0, v1, ah[s], al[s]);
        }
#pragma unroll
        for (int nt = 0; nt < 4; nt++) {
            bh[nt] = *(const short8*)(Bb + (q * 4 + nt) * 1024 + lane * 16);
            bl[nt] = *(const short8*)(Bb + (8 + q * 4 + nt) * 1024 + lane * 16);
        }
#pragma unroll
        for (int s = 0; s < 2; s++)
#pragma unroll
            for (int nt = 0; nt < 4; nt++) {
                acc[s][nt] = __builtin_amdgcn_mfma_f32_16x16x32_bf16(ah[s], bh[nt], acc[s][nt], 0, 0, 0);
                acc[s][nt] = __builtin_amdgcn_mfma_f32_16x16x32_bf16(al[s], bh[nt], acc[s][nt], 0, 0, 0);
                acc[s][nt] = __builtin_amdgcn_mfma_f32_16x16x32_bf16(ah[s], bl[nt], acc[s][nt], 0, 0, 0);
            }
    }
#undef STAGE_A1
#undef STAGE_B1

    // last iter (kt=7) reads Abuf[1]/Bbuf[1]; Abuf[0] last read kt=6, guarded
    // by barrier at top of kt=7; its last stage A(6) retired by wait at kt=6.
    float* sbuf = (float*)Abuf[0];
#pragma unroll
    for (int s = 0; s < 2; s++)
        epi(acc[s], mh * 32 + s * 16, m0, q, lane, bias, attn, Zb, sbuf);
    __syncthreads();
    score_combine(sbuf, tid, m0, sS, sD);
}

// ------- FC2: same asymmetric schedule; A = h1 bf16 (1 chunk/wave, 3x4KB),
// B 2x16KB; total 44KB -> 3 blocks/CU. NT=4; steady wait vmcnt(1). ----

__launch_bounds__(256)
__global__ void gemm_fc2(const unsigned short* __restrict__ Abf,
                         const unsigned short* __restrict__ Whi,
                         const unsigned short* __restrict__ Wlo,
                         const float* __restrict__ bias,
                         const float* __restrict__ attn,
                         unsigned short* __restrict__ Zb,
                         float* __restrict__ sS, float* __restrict__ sD) {
    __shared__ char Abuf[3][4096];
    __shared__ char Bbuf[2][16384];

    int tid  = threadIdx.x;
    int lane = tid & 63;
    int w    = tid >> 6;       // 0..3
    int q    = w & 1;
    int mh   = w >> 1;
    int m0   = blockIdx.x * TM;
    int r    = lane & 15;
    int kg   = lane >> 4;

    // A: 1 chunk/wave (c = w: S=w)
    const char* gpA;
    int loffA;
    {
        int row = m0 + w * 16 + r;
        if (row >= N_NODES) row = N_NODES - 1;
        gpA = (const char*)(Abf + (size_t)row * HID + kg * 8);
        loffA = w * 1024;
    }
    // B: 4 chunks/wave (c = 4w+j; c<8: hi nt=c; else lo nt=c-8)
    const char* gpB[4];
    int loffB[4];
#pragma unroll
    for (int j = 0; j < 4; j++) {
        int c = w * 4 + j;
        loffB[j] = c * 1024;
        if (c < 8) {
            gpB[j] = (const char*)(Whi + (size_t)(c * 16 + r) * HID + kg * 8);
        } else {
            gpB[j] = (const char*)(Wlo + (size_t)((c - 8) * 16 + r) * HID + kg * 8);
        }
    }

#define STAGE_A2(b)                                                 \
    {                                                               \
        GLDS(gpA, Abuf[b] + loffA);                                 \
        gpA += 64;                                                  \
    }
#define STAGE_B2(b)                                                 \
    {                                                               \
        _Pragma("unroll") for (int j = 0; j < 4; j++) {             \
            GLDS(gpB[j], Bbuf[b] + loffB[j]);                       \
            gpB[j] += 64;                                           \
        }                                                           \
    }

    f32x4 acc[2][4];
#pragma unroll
    for (int s = 0; s < 2; s++)
#pragma unroll
        for (int nt = 0; nt < 4; nt++) acc[s][nt] = (f32x4){0.f, 0.f, 0.f, 0.f};

    const int NT = HID / 32;               // 4
    STAGE_A2(0);
    STAGE_B2(0);
    STAGE_A2(1);

#pragma unroll
    for (int kt = 0; kt < NT; kt++) {
        if (kt < NT - 1) {
            asm volatile("s_waitcnt vmcnt(1)" ::: "memory");  // A(kt)+B(kt) done
        } else {
            asm volatile("s_waitcnt vmcnt(0)" ::: "memory");
        }
        __builtin_amdgcn_s_barrier();
        __builtin_amdgcn_sched_barrier(0);
        if (kt + 1 < NT) STAGE_B2((kt + 1) & 1);
        if (kt + 2 < NT) STAGE_A2((kt + 2) % 3);

        const char* Ab = Abuf[kt % 3];
        const char* Bb = Bbuf[kt & 1];

        short8 a8[2], bh[4], bl[4];
#pragma unroll
        for (int s = 0; s < 2; s++)
            a8[s] = *(const short8*)(Ab + (mh * 2 + s) * 1024 + lane * 16);
#pragma unroll
        for (int nt = 0; nt < 4; nt++) {
            bh[nt] = *(const short8*)(Bb + (q * 4 + nt) * 1024 + lane * 16);
            bl[nt] = *(const short8*)(Bb + (8 + q * 4 + nt) * 1024 + lane * 16);
        }
#pragma unroll
        for (int s = 0; s < 2; s++)
#pragma unroll
            for (int nt = 0; nt < 4; nt++) {
                acc[s][nt] = __builtin_amdgcn_mfma_f32_16x16x32_bf16(a8[s], bh[nt], acc[s][nt], 0, 0, 0);
                acc[s][nt] = __builtin_amdgcn_mfma_f32_16x16x32_bf16(a8[s], bl[nt], acc[s][nt], 0, 0, 0);
            }
    }
#undef STAGE_A2
#undef STAGE_B2

    // last iter (kt=3) reads Abuf[0]/Bbuf[1]; Bbuf[0] last read kt=2 -> free.
    float* sbuf = (float*)Bbuf[0];
#pragma unroll
    for (int s = 0; s < 2; s++)
        epi(acc[s], mh * 32 + s * 16, m0, q, lane, bias, attn, Zb, sbuf);
    __syncthreads();
    score_combine(sbuf, tid, m0, sS, sD);
}

// ---------------- segment softmax + weighted gather-sum + ELU ----------------
// one wave per dst node. Fast path: per-edge (src, alpha) in lane registers;
// phase C broadcasts via v_readlane (scalar pipe, no LDS), 16-deep MLP batches.

template <int OUT_BF>
__launch_bounds__(256)
__global__ void aggregate(const unsigned short* __restrict__ Zb,
                          const int* __restrict__ csr_src,
                          const int* __restrict__ offsets,
                          const float* __restrict__ sS,
                          const float* __restrict__ sD,
                          const float* __restrict__ ab,
                          unsigned short* __restrict__ OutBf,
                          float* __restrict__ OutF) {
    int v = blockIdx.x * 4 + (threadIdx.x >> 6);
    int lane = threadIdx.x & 63;
    int off = offsets[v];
    int deg = offsets[v + 1] - off;
    float sdv = sD[v] + ab[0];

    const unsigned int* Zrow = (const unsigned int*)Zb;  // dword = 2 bf16 dims
    float2 acc = {0.f, 0.f};

    if (deg <= 64) {
        bool act = lane < deg;
        int s_l = 0;
        float x = -3.0e38f;
        if (act) {
            s_l = csr_src[off + lane];
            x = lky(sS[s_l] + sdv);
        }
        float mx = x;
#pragma unroll
        for (int o = 32; o > 0; o >>= 1) mx = fmaxf(mx, __shfl_xor(mx, o, 64));
        float ex = act ? __expf(x - mx) : 0.f;
        float sum = ex;
#pragma unroll
        for (int o = 32; o > 0; o >>= 1) sum += __shfl_xor(sum, o, 64);
        float al_l = (deg > 0) ? ex / sum : 0.f;

        int t = 0;
        for (; t + 16 <= deg; t += 16) {
            int   s[16];
            float a[16];
            unsigned int rw[16];
#pragma unroll
            for (int j = 0; j < 16; j++) {
                s[j] = __builtin_amdgcn_readlane(s_l, t + j);
                a[j] = rl_f(al_l, t + j);
            }
#pragma unroll
            for (int j = 0; j < 16; j++)
                rw[j] = Zrow[(size_t)s[j] * (HID / 2) + lane];
#pragma unroll
            for (int j = 0; j < 16; j++) {
                float2 zz = bfu2(rw[j]);
                acc.x += a[j] * zz.x;
                acc.y += a[j] * zz.y;
            }
        }
        for (; t + 4 <= deg; t += 4) {
            int   s[4];
            float a[4];
            unsigned int rw[4];
#pragma unroll
            for (int j = 0; j < 4; j++) {
                s[j] = __builtin_amdgcn_readlane(s_l, t + j);
                a[j] = rl_f(al_l, t + j);
            }
#pragma unroll
            for (int j = 0; j < 4; j++)
                rw[j] = Zrow[(size_t)s[j] * (HID / 2) + lane];
#pragma unroll
            for (int j = 0; j < 4; j++) {
                float2 zz = bfu2(rw[j]);
                acc.x += a[j] * zz.x;
                acc.y += a[j] * zz.y;
            }
        }
        for (; t < deg; t++) {
            int sj = __builtin_amdgcn_readlane(s_l, t);
            float aj = rl_f(al_l, t);
            float2 zz = bfu2(Zrow[(size_t)sj * (HID / 2) + lane]);
            acc.x += aj * zz.x;
            acc.y += aj * zz.y;
        }
    } else {
        float mx = -3.0e38f;
        for (int t = lane; t < deg; t += 64) {
            int s = csr_src[off + t];
            mx = fmaxf(mx, lky(sS[s] + sdv));
        }
#pragma unroll
        for (int o = 32; o > 0; o >>= 1) mx = fmaxf(mx, __shfl_xor(mx, o, 64));
        float sum = 0.f;
        for (int t = lane; t < deg; t += 64) {
            int s = csr_src[off + t];
            sum += __expf(lky(sS[s] + sdv) - mx);
        }
#pragma unroll
        for (int o = 32; o > 0; o >>= 1) sum += __shfl_xor(sum, o, 64);
        float inv = 1.f / sum;
        for (int t = 0; t < deg; t++) {
            int s = csr_src[off + t];
            float al = __expf(lky(sS[s] + sdv) - mx) * inv;
            float2 zz = bfu2(Zrow[(size_t)s * (HID / 2) + lane]);
            acc.x += al * zz.x;
            acc.y += al * zz.y;
        }
    }

    acc.x = acc.x > 0.f ? acc.x : __expf(acc.x) - 1.f;
    acc.y = acc.y > 0.f ? acc.y : __expf(acc.y) - 1.f;

    if (OUT_BF) {
        ushort2 o2;
        o2.x = f2bf(acc.x);
        o2.y = f2bf(acc.y);
        *((ushort2*)(OutBf + (size_t)v * HID + lane * 2)) = o2;
    } else {
        float2 o2 = {acc.x, acc.y};
        *((float2*)(OutF + (size_t)v * HID + lane * 2)) = o2;
    }
}

// ---------------- launch ----------------

extern "C" void kernel_launch(void* const* d_in, const int* in_sizes, int n_in,
                              void* d_out, int out_size, void* d_ws, size_t ws_size,
                              hipStream_t stream) {
    const float* h   = (const float*)d_in[0];
    const int*   src = (const int*)d_in[1];
    const int*   dst = (const int*)d_in[2];
    const float* W1  = (const float*)d_in[3];
    const float* b1  = (const float*)d_in[4];
    const float* a1  = (const float*)d_in[5];
    const float* ab1 = (const float*)d_in[6];
    const float* W2  = (const float*)d_in[7];
    const float* b2  = (const float*)d_in[8];
    const float* a2  = (const float*)d_in[9];
    const float* ab2 = (const float*)d_in[10];
    float* out = (float*)d_out;

    // workspace carve-up (~34 MB)
    unsigned short* zb = (unsigned short*)d_ws;                 // 50000*128 bf16
    float* sS = (float*)(zb + (size_t)N_NODES * HID);           // 50000 f32
    float* sD = sS + N_NODES;                                   // 50000 f32
    int* counts  = (int*)(sD + N_NODES);                        // 50000
    int* offsets = counts + N_NODES;                            // 50001 (+pad)
    int* bsums   = offsets + N_NODES + 16;                      // 256
    unsigned short* h1   = (unsigned short*)(bsums + 256);      // 50000*128 bf16
    unsigned short* w1hi = h1 + (size_t)N_NODES * HID;          // 32768
    unsigned short* w1lo = w1hi + W1_ELEMS;
    unsigned short* w2hi = w1lo + W1_ELEMS;                     // 16384
    unsigned short* w2lo = w2hi + W2_ELEMS;
    int* csr_src = (int*)(w2lo + W2_ELEMS);                     // 800000
    int* erank   = csr_src + N_EDGES;                           // 800000

    hipMemsetAsync(counts, 0, (size_t)N_NODES * sizeof(int), stream);

    // CSR by dst + weight splits; hist returns each edge's in-bucket rank
    hist_split<<<EDGE_BLOCKS, 256, 0, stream>>>(dst, counts, erank,
                                                W1, w1hi, w1lo, W2, w2hi, w2lo);
    scan_block<<<SCAN_BLOCKS, 256, 0, stream>>>(counts, offsets, bsums);
    scan_add<<<SCAN_BLOCKS, 256, 0, stream>>>(offsets, bsums);
    fill_kernel<<<EDGE_BLOCKS, 256, 0, stream>>>(dst, src, erank, offsets, csr_src);

    // layer 1
    gemm_fc1<<<FC_BLOCKS, 256, 0, stream>>>(h, w1hi, w1lo, b1, a1, zb, sS, sD);
    aggregate<1><<<NODE_WBLKS, 256, 0, stream>>>(zb, csr_src, offsets, sS, sD, ab1, h1, nullptr);

    // layer 2
    gemm_fc2<<<FC_BLOCKS, 256, 0, stream>>>(h1, w2hi, w2lo, b2, a2, zb, sS, sD);
    aggregate<0><<<NODE_WBLKS, 256, 0, stream>>>(zb, csr_src, offsets, sS, sD, ab2, nullptr, out);
}

// Round 8
// 280.898 us; speedup vs baseline: 1.0275x; 1.0275x over previous
//
#include <hip/hip_runtime.h>
#include <hip/hip_bf16.h>

#define N_NODES 50000
#define N_EDGES 800000
#define IN_DIM  256
#define HID     128
#define LEAKY   0.01f

#define EDGE_BLOCKS  ((N_EDGES + 255) / 256)      // 3125
#define NODE_WBLKS   (N_NODES / 4)                // 12500
#define SCAN_BLOCKS  ((N_NODES + 255) / 256)      // 196
#define W1_ELEMS  (HID * IN_DIM)                  // 32768
#define W2_ELEMS  (HID * HID)                     // 16384
#define WS_BLOCKS ((W1_ELEMS + W2_ELEMS) / 256)   // 192

#define TM        64                              // GEMM rows per block
#define FC_BLOCKS ((N_NODES + TM - 1) / TM)       // 782

typedef __attribute__((ext_vector_type(8))) short short8;
typedef __attribute__((ext_vector_type(4))) float f32x4;

// async global->LDS, 16B per lane; dest = wave-uniform base + lane*16 (m97 pattern)
#define GLDS(g, l)                                                              \
    __builtin_amdgcn_global_load_lds(                                           \
        (const __attribute__((address_space(1))) void*)(g),                     \
        (__attribute__((address_space(3))) void*)(l), 16, 0, 0)

__device__ __forceinline__ unsigned short f2bf(float x) {
    union { __hip_bfloat16 b; unsigned short u; } c;
    c.b = __float2bfloat16(x);
    return c.u;
}
__device__ __forceinline__ float bf2f(unsigned short u) {
    union { unsigned int u; float f; } c;
    c.u = ((unsigned int)u) << 16;
    return c.f;
}
__device__ __forceinline__ float2 bfu2(unsigned int u) {
    float2 r;
    r.x = bf2f((unsigned short)(u & 0xffff));
    r.y = bf2f((unsigned short)(u >> 16));
    return r;
}
__device__ __forceinline__ float lky(float x) { return x > 0.f ? x : LEAKY * x; }
__device__ __forceinline__ float rl_f(float v, int l) {
    return __int_as_float(__builtin_amdgcn_readlane(__float_as_int(v), l));
}

// split 8 fp32 into bf16 hi/lo (same op order as original -> identical numerics)
__device__ __forceinline__ void cvt8(const float4 v0, const float4 v1,
                                     short8& hi, short8& lo) {
    float f[8] = {v0.x, v0.y, v0.z, v0.w, v1.x, v1.y, v1.z, v1.w};
#pragma unroll
    for (int j = 0; j < 8; j++) {
        unsigned short h = f2bf(f[j]);
        hi[j] = (short)h;
        lo[j] = (short)f2bf(f[j] - bf2f(h));
    }
}

// ------- weight hi/lo splits only (edge hist moved into gemm_fc1) --------

__global__ void wsplit(const float* __restrict__ W1, unsigned short* __restrict__ w1hi,
                       unsigned short* __restrict__ w1lo,
                       const float* __restrict__ W2, unsigned short* __restrict__ w2hi,
                       unsigned short* __restrict__ w2lo) {
    int i = blockIdx.x * 256 + threadIdx.x;
    if (i < W1_ELEMS) {
        float x = W1[i];
        unsigned short h = f2bf(x);
        w1hi[i] = h;
        w1lo[i] = f2bf(x - bf2f(h));
    } else {
        int j = i - W1_ELEMS;                     // j < W2_ELEMS by grid size
        float x = W2[j];
        unsigned short h = f2bf(x);
        w2hi[j] = h;
        w2lo[j] = f2bf(x - bf2f(h));
    }
}

__global__ void scan_block(const int* __restrict__ counts, int* __restrict__ offsets,
                           int* __restrict__ bsums) {
    __shared__ int sh[256];
    int tid = threadIdx.x;
    int i = blockIdx.x * 256 + tid;
    int v = (i < N_NODES) ? counts[i] : 0;
    sh[tid] = v;
    __syncthreads();
    for (int o = 1; o < 256; o <<= 1) {
        int t = (tid >= o) ? sh[tid - o] : 0;
        __syncthreads();
        sh[tid] += t;
        __syncthreads();
    }
    if (i < N_NODES) offsets[i] = sh[tid] - v;
    if (tid == 255) bsums[blockIdx.x] = sh[255];
}

__global__ void scan_add(int* __restrict__ offsets, const int* __restrict__ bsums) {
    __shared__ int sh[256];
    int tid = threadIdx.x;
    int b = blockIdx.x;
    sh[tid] = (tid < b) ? bsums[tid] : 0;   // b <= 195 < 256
    __syncthreads();
    for (int o = 128; o > 0; o >>= 1) {
        if (tid < o) sh[tid] += sh[tid + o];
        __syncthreads();
    }
    int base = sh[0];
    int i = b * 256 + tid;
    if (i < N_NODES) offsets[i] += base;
    if (i == N_NODES) offsets[N_NODES] = N_EDGES;
}

// fill: atomic-free scatter; nontemporal store avoids cross-XCD L2 line bounce
__global__ void fill_kernel(const int* __restrict__ dst, const int* __restrict__ src,
                            const int* __restrict__ erank,
                            const int* __restrict__ offsets,
                            int* __restrict__ csr_src) {
    int i = blockIdx.x * 256 + threadIdx.x;
    if (i < N_EDGES) {
        int d = dst[i];
        int slot = offsets[d] + erank[i];
        __builtin_nontemporal_store(src[i], &csr_src[slot]);
    }
}

// ---------------- epilogue for one 16-row subtile ----------------
// C/D: col = lane&15, row = (lane>>4)*4 + reg. Partial scores reduce over r
// via shfl_xor, then land in sbuf[q*128 + {0:S,64:D} + lrow] for block-combine.

__device__ __forceinline__ void epi(const f32x4* accn, int lrow0, int m0, int q, int lane,
                                    const float* __restrict__ bias,
                                    const float* __restrict__ attn,
                                    unsigned short* __restrict__ Zb,
                                    float* __restrict__ sbuf) {
    int r = lane & 15;
    int lrowbase = lrow0 + (lane >> 4) * 4;   // 0..63 within block
    float ps[4] = {0.f, 0.f, 0.f, 0.f};
    float pd[4] = {0.f, 0.f, 0.f, 0.f};
#pragma unroll
    for (int nt = 0; nt < 4; nt++) {
        int n = q * 64 + nt * 16 + r;
        float bn = bias[n];
        float aS = attn[n];
        float aD = attn[HID + n];
#pragma unroll
        for (int reg = 0; reg < 4; reg++) {
            float zv = accn[nt][reg] + bn;
            if (m0 + lrowbase + reg < N_NODES)
                Zb[(size_t)(m0 + lrowbase + reg) * HID + n] = f2bf(zv);
            ps[reg] += zv * aS;
            pd[reg] += zv * aD;
        }
    }
#pragma unroll
    for (int o = 1; o < 16; o <<= 1) {
#pragma unroll
        for (int reg = 0; reg < 4; reg++) {
            ps[reg] += __shfl_xor(ps[reg], o, 64);
            pd[reg] += __shfl_xor(pd[reg], o, 64);
        }
    }
    if (r == 0) {
#pragma unroll
        for (int reg = 0; reg < 4; reg++) {
            sbuf[q * 128 + lrowbase + reg] = ps[reg];
            sbuf[q * 128 + 64 + lrowbase + reg] = pd[reg];
        }
    }
}

// combine q-halves and store single score planes
__device__ __forceinline__ void score_combine(const float* __restrict__ sbuf, int tid, int m0,
                                              float* __restrict__ sS, float* __restrict__ sD) {
    if (tid < TM) {
        int gr = m0 + tid;
        if (gr < N_NODES) {
            sS[gr] = sbuf[tid] + sbuf[128 + tid];
            sD[gr] = sbuf[64 + tid] + sbuf[128 + 64 + tid];
        }
    }
}

// ------- FC1: R7's asymmetric counted-vmcnt schedule (best known) + FUSED
// edge histogram. fc1 is ~90% idle (MfmaUtil 8 / VALU 11 / HBM 12): the 800K
// random atomicAdd round-trips ride in the stall slack. 4 edges/thread x
// 782 blocks x 256 thr = 800,768 slots. Atomics issue right after the
// prologue stage so their latency overlaps the first A-load; they only
// tighten the first counted wait (older ops retire within the prologue
// shadow). scan_block runs after fc1 -> stream order guarantees done. -------

__launch_bounds__(256)
__global__ void gemm_fc1(const float* __restrict__ A,
                         const unsigned short* __restrict__ Whi,
                         const unsigned short* __restrict__ Wlo,
                         const float* __restrict__ bias,
                         const float* __restrict__ attn,
                         const int* __restrict__ dst, int* __restrict__ counts,
                         int* __restrict__ erank,
                         unsigned short* __restrict__ Zb,
                         float* __restrict__ sS, float* __restrict__ sD) {
    __shared__ char Abuf[3][8192];
    __shared__ char Bbuf[2][16384];

    int tid  = threadIdx.x;
    int lane = tid & 63;
    int w    = tid >> 6;       // 0..3
    int q    = w & 1;
    int mh   = w >> 1;
    int m0   = blockIdx.x * TM;
    int r    = lane & 15;
    int kg   = lane >> 4;

    // A: 2 chunks/wave (c = 2w+j: S=w, half=j). fragment-order (R4-verified).
    const char* gpA[2];
    int loffA[2];
#pragma unroll
    for (int j = 0; j < 2; j++) {
        int row = m0 + w * 16 + r;
        if (row >= N_NODES) row = N_NODES - 1;
        gpA[j] = (const char*)(A + (size_t)row * IN_DIM + kg * 8 + j * 4);
        loffA[j] = (w * 2 + j) * 1024;
    }
    // B: 4 chunks/wave (c = 4w+j; c<8: hi nt=c; else lo nt=c-8).
    const char* gpB[4];
    int loffB[4];
#pragma unroll
    for (int j = 0; j < 4; j++) {
        int c = w * 4 + j;
        loffB[j] = c * 1024;
        if (c < 8) {
            gpB[j] = (const char*)(Whi + (size_t)(c * 16 + r) * IN_DIM + kg * 8);
        } else {
            gpB[j] = (const char*)(Wlo + (size_t)((c - 8) * 16 + r) * IN_DIM + kg * 8);
        }
    }

#define STAGE_A1(b)                                                 \
    {                                                               \
        _Pragma("unroll") for (int j = 0; j < 2; j++) {             \
            GLDS(gpA[j], Abuf[b] + loffA[j]);                       \
            gpA[j] += 128;                                          \
        }                                                           \
    }
#define STAGE_B1(b)                                                 \
    {                                                               \
        _Pragma("unroll") for (int j = 0; j < 4; j++) {             \
            GLDS(gpB[j], Bbuf[b] + loffB[j]);                       \
            gpB[j] += 64;                                           \
        }                                                           \
    }

    f32x4 acc[2][4];
#pragma unroll
    for (int s = 0; s < 2; s++)
#pragma unroll
        for (int nt = 0; nt < 4; nt++) acc[s][nt] = (f32x4){0.f, 0.f, 0.f, 0.f};

    const int NT = IN_DIM / 32;            // 8
    STAGE_A1(0);
    STAGE_B1(0);
    STAGE_A1(1);

    // ---- fused edge histogram: latency hidden under the prologue/K-loop ----
    {
        int e0 = (blockIdx.x * 256 + tid) * 4;
#pragma unroll
        for (int j = 0; j < 4; j++) {
            int e = e0 + j;
            if (e < N_EDGES) erank[e] = atomicAdd(&counts[dst[e]], 1);
        }
    }

#pragma unroll
    for (int kt = 0; kt < NT; kt++) {
        if (kt < NT - 1) {
            asm volatile("s_waitcnt vmcnt(2)" ::: "memory");  // A(kt)+B(kt) done
        } else {
            asm volatile("s_waitcnt vmcnt(0)" ::: "memory");
        }
        __builtin_amdgcn_s_barrier();
        __builtin_amdgcn_sched_barrier(0);
        if (kt + 1 < NT) STAGE_B1((kt + 1) & 1);      // after barrier: race-free
        if (kt + 2 < NT) STAGE_A1((kt + 2) % 3);

        const char* Ab = Abuf[kt % 3];
        const char* Bb = Bbuf[kt & 1];

        short8 ah[2], al[2], bh[4], bl[4];
#pragma unroll
        for (int s = 0; s < 2; s++) {
            int S = mh * 2 + s;
            float4 v0 = *(const float4*)(Ab + (S * 2 + 0) * 1024 + lane * 16);
            float4 v1 = *(const float4*)(Ab + (S * 2 + 1) * 1024 + lane * 16);
            cvt8(v0, v1, ah[s], al[s]);
        }
#pragma unroll
        for (int nt = 0; nt < 4; nt++) {
            bh[nt] = *(const short8*)(Bb + (q * 4 + nt) * 1024 + lane * 16);
            bl[nt] = *(const short8*)(Bb + (8 + q * 4 + nt) * 1024 + lane * 16);
        }
#pragma unroll
        for (int s = 0; s < 2; s++)
#pragma unroll
            for (int nt = 0; nt < 4; nt++) {
                acc[s][nt] = __builtin_amdgcn_mfma_f32_16x16x32_bf16(ah[s], bh[nt], acc[s][nt], 0, 0, 0);
                acc[s][nt] = __builtin_amdgcn_mfma_f32_16x16x32_bf16(al[s], bh[nt], acc[s][nt], 0, 0, 0);
                acc[s][nt] = __builtin_amdgcn_mfma_f32_16x16x32_bf16(ah[s], bl[nt], acc[s][nt], 0, 0, 0);
            }
    }
#undef STAGE_A1
#undef STAGE_B1

    // last iter (kt=7) reads Abuf[1]/Bbuf[1]; Abuf[0] free after barrier kt=7.
    float* sbuf = (float*)Abuf[0];
#pragma unroll
    for (int s = 0; s < 2; s++)
        epi(acc[s], mh * 32 + s * 16, m0, q, lane, bias, attn, Zb, sbuf);
    __syncthreads();
    score_combine(sbuf, tid, m0, sS, sD);
}

// ------- FC2: R7 asymmetric schedule (unchanged); A = h1 bf16 (3x4KB),
// B 2x16KB; total 44KB -> 3 blocks/CU. NT=4; steady wait vmcnt(1). ----

__launch_bounds__(256)
__global__ void gemm_fc2(const unsigned short* __restrict__ Abf,
                         const unsigned short* __restrict__ Whi,
                         const unsigned short* __restrict__ Wlo,
                         const float* __restrict__ bias,
                         const float* __restrict__ attn,
                         unsigned short* __restrict__ Zb,
                         float* __restrict__ sS, float* __restrict__ sD) {
    __shared__ char Abuf[3][4096];
    __shared__ char Bbuf[2][16384];

    int tid  = threadIdx.x;
    int lane = tid & 63;
    int w    = tid >> 6;       // 0..3
    int q    = w & 1;
    int mh   = w >> 1;
    int m0   = blockIdx.x * TM;
    int r    = lane & 15;
    int kg   = lane >> 4;

    // A: 1 chunk/wave (c = w: S=w)
    const char* gpA;
    int loffA;
    {
        int row = m0 + w * 16 + r;
        if (row >= N_NODES) row = N_NODES - 1;
        gpA = (const char*)(Abf + (size_t)row * HID + kg * 8);
        loffA = w * 1024;
    }
    // B: 4 chunks/wave (c = 4w+j; c<8: hi nt=c; else lo nt=c-8)
    const char* gpB[4];
    int loffB[4];
#pragma unroll
    for (int j = 0; j < 4; j++) {
        int c = w * 4 + j;
        loffB[j] = c * 1024;
        if (c < 8) {
            gpB[j] = (const char*)(Whi + (size_t)(c * 16 + r) * HID + kg * 8);
        } else {
            gpB[j] = (const char*)(Wlo + (size_t)((c - 8) * 16 + r) * HID + kg * 8);
        }
    }

#define STAGE_A2(b)                                                 \
    {                                                               \
        GLDS(gpA, Abuf[b] + loffA);                                 \
        gpA += 64;                                                  \
    }
#define STAGE_B2(b)                                                 \
    {                                                               \
        _Pragma("unroll") for (int j = 0; j < 4; j++) {             \
            GLDS(gpB[j], Bbuf[b] + loffB[j]);                       \
            gpB[j] += 64;                                           \
        }                                                           \
    }

    f32x4 acc[2][4];
#pragma unroll
    for (int s = 0; s < 2; s++)
#pragma unroll
        for (int nt = 0; nt < 4; nt++) acc[s][nt] = (f32x4){0.f, 0.f, 0.f, 0.f};

    const int NT = HID / 32;               // 4
    STAGE_A2(0);
    STAGE_B2(0);
    STAGE_A2(1);

#pragma unroll
    for (int kt = 0; kt < NT; kt++) {
        if (kt < NT - 1) {
            asm volatile("s_waitcnt vmcnt(1)" ::: "memory");  // A(kt)+B(kt) done
        } else {
            asm volatile("s_waitcnt vmcnt(0)" ::: "memory");
        }
        __builtin_amdgcn_s_barrier();
        __builtin_amdgcn_sched_barrier(0);
        if (kt + 1 < NT) STAGE_B2((kt + 1) & 1);
        if (kt + 2 < NT) STAGE_A2((kt + 2) % 3);

        const char* Ab = Abuf[kt % 3];
        const char* Bb = Bbuf[kt & 1];

        short8 a8[2], bh[4], bl[4];
#pragma unroll
        for (int s = 0; s < 2; s++)
            a8[s] = *(const short8*)(Ab + (mh * 2 + s) * 1024 + lane * 16);
#pragma unroll
        for (int nt = 0; nt < 4; nt++) {
            bh[nt] = *(const short8*)(Bb + (q * 4 + nt) * 1024 + lane * 16);
            bl[nt] = *(const short8*)(Bb + (8 + q * 4 + nt) * 1024 + lane * 16);
        }
#pragma unroll
        for (int s = 0; s < 2; s++)
#pragma unroll
            for (int nt = 0; nt < 4; nt++) {
                acc[s][nt] = __builtin_amdgcn_mfma_f32_16x16x32_bf16(a8[s], bh[nt], acc[s][nt], 0, 0, 0);
                acc[s][nt] = __builtin_amdgcn_mfma_f32_16x16x32_bf16(a8[s], bl[nt], acc[s][nt], 0, 0, 0);
            }
    }
#undef STAGE_A2
#undef STAGE_B2

    // last iter (kt=3) reads Abuf[0]/Bbuf[1]; Bbuf[0] last read kt=2 -> free.
    float* sbuf = (float*)Bbuf[0];
#pragma unroll
    for (int s = 0; s < 2; s++)
        epi(acc[s], mh * 32 + s * 16, m0, q, lane, bias, attn, Zb, sbuf);
    __syncthreads();
    score_combine(sbuf, tid, m0, sS, sD);
}

// ---------------- segment softmax + weighted gather-sum + ELU ----------------
// one wave per dst node. Fast path: per-edge (src, alpha) in lane registers;
// phase C broadcasts via v_readlane (scalar pipe, no LDS), 16-deep MLP batches.

template <int OUT_BF>
__launch_bounds__(256)
__global__ void aggregate(const unsigned short* __restrict__ Zb,
                          const int* __restrict__ csr_src,
                          const int* __restrict__ offsets,
                          const float* __restrict__ sS,
                          const float* __restrict__ sD,
                          const float* __restrict__ ab,
                          unsigned short* __restrict__ OutBf,
                          float* __restrict__ OutF) {
    int v = blockIdx.x * 4 + (threadIdx.x >> 6);
    int lane = threadIdx.x & 63;
    int off = offsets[v];
    int deg = offsets[v + 1] - off;
    float sdv = sD[v] + ab[0];

    const unsigned int* Zrow = (const unsigned int*)Zb;  // dword = 2 bf16 dims
    float2 acc = {0.f, 0.f};

    if (deg <= 64) {
        bool act = lane < deg;
        int s_l = 0;
        float x = -3.0e38f;
        if (act) {
            s_l = csr_src[off + lane];
            x = lky(sS[s_l] + sdv);
        }
        float mx = x;
#pragma unroll
        for (int o = 32; o > 0; o >>= 1) mx = fmaxf(mx, __shfl_xor(mx, o, 64));
        float ex = act ? __expf(x - mx) : 0.f;
        float sum = ex;
#pragma unroll
        for (int o = 32; o > 0; o >>= 1) sum += __shfl_xor(sum, o, 64);
        float al_l = (deg > 0) ? ex / sum : 0.f;

        int t = 0;
        for (; t + 16 <= deg; t += 16) {
            int   s[16];
            float a[16];
            unsigned int rw[16];
#pragma unroll
            for (int j = 0; j < 16; j++) {
                s[j] = __builtin_amdgcn_readlane(s_l, t + j);
                a[j] = rl_f(al_l, t + j);
            }
#pragma unroll
            for (int j = 0; j < 16; j++)
                rw[j] = Zrow[(size_t)s[j] * (HID / 2) + lane];
#pragma unroll
            for (int j = 0; j < 16; j++) {
                float2 zz = bfu2(rw[j]);
                acc.x += a[j] * zz.x;
                acc.y += a[j] * zz.y;
            }
        }
        for (; t + 4 <= deg; t += 4) {
            int   s[4];
            float a[4];
            unsigned int rw[4];
#pragma unroll
            for (int j = 0; j < 4; j++) {
                s[j] = __builtin_amdgcn_readlane(s_l, t + j);
                a[j] = rl_f(al_l, t + j);
            }
#pragma unroll
            for (int j = 0; j < 4; j++)
                rw[j] = Zrow[(size_t)s[j] * (HID / 2) + lane];
#pragma unroll
            for (int j = 0; j < 4; j++) {
                float2 zz = bfu2(rw[j]);
                acc.x += a[j] * zz.x;
                acc.y += a[j] * zz.y;
            }
        }
        for (; t < deg; t++) {
            int sj = __builtin_amdgcn_readlane(s_l, t);
            float aj = rl_f(al_l, t);
            float2 zz = bfu2(Zrow[(size_t)sj * (HID / 2) + lane]);
            acc.x += aj * zz.x;
            acc.y += aj * zz.y;
        }
    } else {
        float mx = -3.0e38f;
        for (int t = lane; t < deg; t += 64) {
            int s = csr_src[off + t];
            mx = fmaxf(mx, lky(sS[s] + sdv));
        }
#pragma unroll
        for (int o = 32; o > 0; o >>= 1) mx = fmaxf(mx, __shfl_xor(mx, o, 64));
        float sum = 0.f;
        for (int t = lane; t < deg; t += 64) {
            int s = csr_src[off + t];
            sum += __expf(lky(sS[s] + sdv) - mx);
        }
#pragma unroll
        for (int o = 32; o > 0; o >>= 1) sum += __shfl_xor(sum, o, 64);
        float inv = 1.f / sum;
        for (int t = 0; t < deg; t++) {
            int s = csr_src[off + t];
            float al = __expf(lky(sS[s] + sdv) - mx) * inv;
            float2 zz = bfu2(Zrow[(size_t)s * (HID / 2) + lane]);
            acc.x += al * zz.x;
            acc.y += al * zz.y;
        }
    }

    acc.x = acc.x > 0.f ? acc.x : __expf(acc.x) - 1.f;
    acc.y = acc.y > 0.f ? acc.y : __expf(acc.y) - 1.f;

    if (OUT_BF) {
        ushort2 o2;
        o2.x = f2bf(acc.x);
        o2.y = f2bf(acc.y);
        *((ushort2*)(OutBf + (size_t)v * HID + lane * 2)) = o2;
    } else {
        float2 o2 = {acc.x, acc.y};
        *((float2*)(OutF + (size_t)v * HID + lane * 2)) = o2;
    }
}

// ---------------- launch ----------------

extern "C" void kernel_launch(void* const* d_in, const int* in_sizes, int n_in,
                              void* d_out, int out_size, void* d_ws, size_t ws_size,
                              hipStream_t stream) {
    const float* h   = (const float*)d_in[0];
    const int*   src = (const int*)d_in[1];
    const int*   dst = (const int*)d_in[2];
    const float* W1  = (const float*)d_in[3];
    const float* b1  = (const float*)d_in[4];
    const float* a1  = (const float*)d_in[5];
    const float* ab1 = (const float*)d_in[6];
    const float* W2  = (const float*)d_in[7];
    const float* b2  = (const float*)d_in[8];
    const float* a2  = (const float*)d_in[9];
    const float* ab2 = (const float*)d_in[10];
    float* out = (float*)d_out;

    // workspace carve-up (~34 MB)
    unsigned short* zb = (unsigned short*)d_ws;                 // 50000*128 bf16
    float* sS = (float*)(zb + (size_t)N_NODES * HID);           // 50000 f32
    float* sD = sS + N_NODES;                                   // 50000 f32
    int* counts  = (int*)(sD + N_NODES);                        // 50000
    int* offsets = counts + N_NODES;                            // 50001 (+pad)
    int* bsums   = offsets + N_NODES + 16;                      // 256
    unsigned short* h1   = (unsigned short*)(bsums + 256);      // 50000*128 bf16
    unsigned short* w1hi = h1 + (size_t)N_NODES * HID;          // 32768
    unsigned short* w1lo = w1hi + W1_ELEMS;
    unsigned short* w2hi = w1lo + W1_ELEMS;                     // 16384
    unsigned short* w2lo = w2hi + W2_ELEMS;
    int* csr_src = (int*)(w2lo + W2_ELEMS);                     // 800000
    int* erank   = csr_src + N_EDGES;                           // 800000

    hipMemsetAsync(counts, 0, (size_t)N_NODES * sizeof(int), stream);

    // weight splits (must precede fc1, which consumes the planes)
    wsplit<<<WS_BLOCKS, 256, 0, stream>>>(W1, w1hi, w1lo, W2, w2hi, w2lo);

    // layer 1 GEMM + fused edge histogram (hist latency hidden in GEMM stalls)
    gemm_fc1<<<FC_BLOCKS, 256, 0, stream>>>(h, w1hi, w1lo, b1, a1,
                                            dst, counts, erank, zb, sS, sD);

    // CSR finalize (stream order guarantees fc1's atomics complete)
    scan_block<<<SCAN_BLOCKS, 256, 0, stream>>>(counts, offsets, bsums);
    scan_add<<<SCAN_BLOCKS, 256, 0, stream>>>(offsets, bsums);
    fill_kernel<<<EDGE_BLOCKS, 256, 0, stream>>>(dst, src, erank, offsets, csr_src);

    aggregate<1><<<NODE_WBLKS, 256, 0, stream>>>(zb, csr_src, offsets, sS, sD, ab1, h1, nullptr);

    // layer 2
    gemm_fc2<<<FC_BLOCKS, 256, 0, stream>>>(h1, w2hi, w2lo, b2, a2, zb, sS, sD);
    aggregate<0><<<NODE_WBLKS, 256, 0, stream>>>(zb, csr_src, offsets, sS, sD, ab2, nullptr, out);
}